// Round 9
// baseline (121.837 us; speedup 1.0000x reference)
//
#include <hip/hip_runtime.h>

// LearnedTaskSpecificLinear: out[n,o] = sum_i x[n,i] * W[task_ids[n], i, o]
// x: [2048,512] f32, task_ids: [2048] i32, W: [64,512,512] f32, out: [2048,512] f32
//
// Round 9: R8 barrier-free shape + explicit depth-2 software pipeline on the
// global W/x loads (R7/R8 diagnosis: compiler serialized the strided dword
// gathers at VGPR 32 -> MLP-capped ~2 TB/s; force ~24 loads in flight/lane).
//   K1 (1 block): histogram tids -> padded 16-row groups (prow, gtask).
//   K2: grid (16 col-chunks of 32, 48 group-quads) x 256 thr; wave = one
//       group (16 rows) x 32 cols x K=512; 16 kf steps, each 2x mfma 16x16x32.
//       Loads for kf+1 issued before consuming kf (rolling regs, full unroll).
//       B cols ml / ml+16 -> full 128-B lines. No LDS data, no barriers.

#define NDIM 512
#define KDIM 512
#define MAXG 192

typedef _Float16 f16x8 __attribute__((ext_vector_type(8)));
typedef float    f32x4 __attribute__((ext_vector_type(4)));

__global__ __launch_bounds__(256) void k_groups(
    const int* __restrict__ tids, int n_rows,
    int* __restrict__ gtask, unsigned short* __restrict__ prow)
{
    __shared__ int cnt[64], pos[64], gbase[64];
    const int tid = threadIdx.x;
    if (tid < 64) { cnt[tid] = 0; pos[tid] = 0; }
    __syncthreads();
    for (int i = tid; i < n_rows; i += 256)
        atomicAdd(&cnt[tids[i]], 1);
    __syncthreads();
    if (tid == 0) {
        int off = 0;
        for (int t = 0; t < 64; ++t) {
            gbase[t] = off;
            off += (cnt[t] + 15) >> 4;
        }
    }
    __syncthreads();
    for (int i = tid; i < MAXG * 16; i += 256) prow[i] = 0xFFFFu;
    if (tid < MAXG) gtask[tid] = -1;
    __syncthreads();
    if (tid < 64) {
        const int ng = (cnt[tid] + 15) >> 4;
        for (int g = 0; g < ng; ++g) gtask[gbase[tid] + g] = tid;
    }
    for (int i = tid; i < n_rows; i += 256) {
        const int t = tids[i];
        const int p = atomicAdd(&pos[t], 1);
        prow[gbase[t] * 16 + p] = (unsigned short)i;
    }
}

__global__ __launch_bounds__(256, 3) void k_gemm(
    const float* __restrict__ x, const float* __restrict__ W,
    const int* __restrict__ gtask, const unsigned short* __restrict__ prow,
    float* __restrict__ out)
{
    const int tid  = threadIdx.x;
    const int lane = tid & 63;
    const int wv   = tid >> 6;
    const int ml   = lane & 15;
    const int q    = lane >> 4;
    const int c0   = blockIdx.x * 32;
    const int g    = blockIdx.y * 4 + wv;

    const int task = gtask[g];
    if (task < 0) return;                     // wave-uniform; no barriers in kernel

    const int rowreg = prow[g * 16 + ml];     // 0xFFFF = pad
    const int xrow   = (rowreg == 0xFFFF) ? 0 : rowreg;
    const float* xp = x + (size_t)xrow * KDIM + q * 8;
    const float* Wp = W + (size_t)task * KDIM * NDIM + (size_t)(q * 8) * NDIM + c0 + ml;

    // ---- prologue: load kf=0 batch
    float  b0[8], b1[8];
    float4 a0, a1;
    #pragma unroll
    for (int j = 0; j < 8; ++j) {
        b0[j] = Wp[(size_t)j * NDIM];
        b1[j] = Wp[(size_t)j * NDIM + 16];
    }
    a0 = *(const float4*)(xp);
    a1 = *(const float4*)(xp + 4);

    f32x4 acc0 = {}, acc1 = {};

    #pragma unroll
    for (int kf = 0; kf < 16; ++kf) {
        // ---- issue kf+1 loads BEFORE consuming kf (depth-2 pipeline)
        float  nb0[8], nb1[8];
        float4 na0, na1;
        if (kf < 15) {
            const float* wk = Wp + (size_t)(kf + 1) * 32 * NDIM;
            #pragma unroll
            for (int j = 0; j < 8; ++j) {
                nb0[j] = wk[(size_t)j * NDIM];
                nb1[j] = wk[(size_t)j * NDIM + 16];
            }
            na0 = *(const float4*)(xp + (kf + 1) * 32);
            na1 = *(const float4*)(xp + (kf + 1) * 32 + 4);
        }

        // ---- convert + 2 MFMA on current batch
        f16x8 af, bf0, bf1;
        af[0] = (_Float16)a0.x; af[1] = (_Float16)a0.y;
        af[2] = (_Float16)a0.z; af[3] = (_Float16)a0.w;
        af[4] = (_Float16)a1.x; af[5] = (_Float16)a1.y;
        af[6] = (_Float16)a1.z; af[7] = (_Float16)a1.w;
        #pragma unroll
        for (int j = 0; j < 8; ++j) {
            bf0[j] = (_Float16)b0[j];
            bf1[j] = (_Float16)b1[j];
        }
        acc0 = __builtin_amdgcn_mfma_f32_16x16x32_f16(af, bf0, acc0, 0, 0, 0);
        acc1 = __builtin_amdgcn_mfma_f32_16x16x32_f16(af, bf1, acc1, 0, 0, 0);

        // ---- rotate (register renames after unroll)
        if (kf < 15) {
            #pragma unroll
            for (int j = 0; j < 8; ++j) { b0[j] = nb0[j]; b1[j] = nb1[j]; }
            a0 = na0; a1 = na1;
        }
    }

    // ---- store: D row = q*4+r2 (group-local), col = ml (+16); rows via shfl
    #pragma unroll
    for (int r2 = 0; r2 < 4; ++r2) {
        const int src  = q * 4 + r2;
        const int orow = __shfl(rowreg, src);
        if (orow != 0xFFFF) {
            out[(size_t)orow * NDIM + c0 + ml]      = acc0[r2];
            out[(size_t)orow * NDIM + c0 + 16 + ml] = acc1[r2];
        }
    }
}

extern "C" void kernel_launch(void* const* d_in, const int* in_sizes, int n_in,
                              void* d_out, int out_size, void* d_ws, size_t ws_size,
                              hipStream_t stream) {
    const float* x    = (const float*)d_in[0];
    const int*   tids = (const int*)d_in[1];
    const float* W    = (const float*)d_in[2];
    float*       out  = (float*)d_out;
    const int n_rows  = in_sizes[1];   // 2048

    int*            gtask = (int*)d_ws;                              // 192 ints
    unsigned short* prow  = (unsigned short*)((char*)d_ws + 1024);   // 192*16 ushort

    k_groups<<<dim3(1), dim3(256), 0, stream>>>(tids, n_rows, gtask, prow);
    k_gemm<<<dim3(NDIM / 32, MAXG / 4), dim3(256), 0, stream>>>(x, W, gtask, prow, out);
}

// Round 10
// 112.067 us; speedup vs baseline: 1.0872x; 1.0872x over previous
//
#include <hip/hip_runtime.h>

// LearnedTaskSpecificLinear: out[n,o] = sum_i x[n,i] * W[task_ids[n], i, o]
// x: [2048,512] f32, task_ids: [2048] i32, W: [64,512,512] f32, out: [2048,512] f32
//
// Round 10: k_groups prologue + fine-generation LDS-staged MFMA.
//   Evidence: bulk homogeneous staging loads stay in flight (R5/R6 VGPR 148);
//   load->consume pipelines get re-serialized (R9 VGPR 36). So: W goes through
//   LDS via bulk loads; everything else direct.
//   K2 grid (16 col-chunks of 32, 64 tasks) = 1024 blocks x 256 thr (4 waves).
//   Block = one task x 32 cols x up to 64 rows/pass (wave = 16 rows).
//   K-loop: 4 generations of KT=128: per thread 4 strided float4 W loads ->
//   f16 cvt -> b64 LDS writes; atom layout Wt[(oct*33 + c)*8] (pad 33: write
//   b64 and read b128 both exactly at bank floor). Next gen's W loads issued
//   between barriers (vmcnt overlaps MFMA phase). A-frags from global x
//   (f32->f16 in-register), 8 mfma_16x16x32_f16 per wave per gen. No ballot,
//   no compaction in hot kernel, no cross-wave reduce. W read once from HBM.

#define NDIM 512
#define KDIM 512

typedef _Float16 f16x8 __attribute__((ext_vector_type(8)));
typedef _Float16 f16x4 __attribute__((ext_vector_type(4)));
typedef float    f32x4 __attribute__((ext_vector_type(4)));

__global__ __launch_bounds__(256) void k_groups(
    const int* __restrict__ tids, int n_rows,
    int* __restrict__ gcnt, unsigned short* __restrict__ rows)
{
    __shared__ int cnt[64];
    const int tid = threadIdx.x;
    if (tid < 64) cnt[tid] = 0;
    __syncthreads();
    for (int i = tid; i < n_rows; i += 256) {
        const int t = tids[i];
        const int p = atomicAdd(&cnt[t], 1);
        rows[t * 2048 + p] = (unsigned short)i;
    }
    __syncthreads();
    if (tid < 64) gcnt[tid] = cnt[tid];
}

__global__ __launch_bounds__(256, 4) void k_gemm(
    const float* __restrict__ x, const float* __restrict__ W,
    const int* __restrict__ gcnt, const unsigned short* __restrict__ rows,
    float* __restrict__ out)
{
    const int tid  = threadIdx.x;
    const int lane = tid & 63;
    const int wv   = tid >> 6;
    const int ml   = lane & 15;
    const int q    = lane >> 4;
    const int c0   = blockIdx.x * 32;
    const int task = blockIdx.y;

    const int count = gcnt[task];
    if (count == 0) return;                 // block-uniform, before any barrier
    const int nh = (count + 63) >> 6;

    __shared__ __align__(16) _Float16 Wt[16 * 33 * 8];   // 8448 B, atom layout

    const float*          Wg = W + (size_t)task * KDIM * NDIM + c0;
    const unsigned short* rt = rows + task * 2048;

    // staging coords: thread covers k-quad krun (4 k) x cols sc4..sc4+3
    const int krun = tid >> 3;              // 0..31
    const int sc4  = (tid & 7) * 4;

    for (int h = 0; h < nh; ++h) {
        const int j0 = h * 64 + wv * 16;
        const int jj = j0 + ml;
        const int rowreg = (jj < count) ? (int)rt[jj] : 0xFFFF;
        const int xrow   = (rowreg == 0xFFFF) ? 0 : rowreg;
        const float* xp  = x + (size_t)xrow * KDIM;
        const bool wactive = (j0 < count);  // wave-uniform

        f32x4 acc0 = {}, acc1 = {};

        // prologue: bulk W loads for gen 0 (stride-NDIM float4 block — the
        // R5-proven pattern the compiler keeps in flight)
        float4 wr[4];
        #pragma unroll
        for (int j = 0; j < 4; ++j)
            wr[j] = *(const float4*)(Wg + (size_t)(krun * 4 + j) * NDIM + sc4);

        #pragma unroll
        for (int gen = 0; gen < 4; ++gen) {
            const int kb = gen * 128;

            // ---- cvt + swizzled b64 LDS writes (bank-floor uniform residues)
            #pragma unroll
            for (int j2 = 0; j2 < 4; ++j2) {
                f16x4 v = {(_Float16)(((const float*)&wr[0])[j2]),
                           (_Float16)(((const float*)&wr[1])[j2]),
                           (_Float16)(((const float*)&wr[2])[j2]),
                           (_Float16)(((const float*)&wr[3])[j2])};
                const int c   = sc4 + j2;
                const int idx = (((krun >> 1) * 33) + c) * 8 + (krun & 1) * 4;
                *(f16x4*)&Wt[idx] = v;
            }
            __syncthreads();

            // ---- issue NEXT gen's bulk W loads (vmcnt overlaps MFMA phase)
            float4 nwr[4];
            if (gen < 3) {
                #pragma unroll
                for (int j = 0; j < 4; ++j)
                    nwr[j] = *(const float4*)(Wg + (size_t)(kb + 128 + krun * 4 + j) * NDIM + sc4);
            }

            // ---- compute: 4 K-steps x 2 col-tiles
            if (wactive) {
                #pragma unroll
                for (int ks = 0; ks < 4; ++ks) {
                    const float4 a0 = *(const float4*)(xp + kb + ks * 32 + q * 8);
                    const float4 a1 = *(const float4*)(xp + kb + ks * 32 + q * 8 + 4);
                    f16x8 af;
                    af[0] = (_Float16)a0.x; af[1] = (_Float16)a0.y;
                    af[2] = (_Float16)a0.z; af[3] = (_Float16)a0.w;
                    af[4] = (_Float16)a1.x; af[5] = (_Float16)a1.y;
                    af[6] = (_Float16)a1.z; af[7] = (_Float16)a1.w;
                    const int oct = ks * 4 + q;
                    const f16x8 bf0 = *(const f16x8*)&Wt[(oct * 33 + ml) * 8];
                    const f16x8 bf1 = *(const f16x8*)&Wt[(oct * 33 + 16 + ml) * 8];
                    acc0 = __builtin_amdgcn_mfma_f32_16x16x32_f16(af, bf0, acc0, 0, 0, 0);
                    acc1 = __builtin_amdgcn_mfma_f32_16x16x32_f16(af, bf1, acc1, 0, 0, 0);
                }
            }
            __syncthreads();

            if (gen < 3) {
                #pragma unroll
                for (int j = 0; j < 4; ++j) wr[j] = nwr[j];
            }
        }

        // ---- store: D row = q*4+rg (group-local), col = ml (+16); rows via shfl
        if (wactive) {
            #pragma unroll
            for (int rg = 0; rg < 4; ++rg) {
                const int orow = __shfl(rowreg, q * 4 + rg);
                if (orow != 0xFFFF) {
                    out[(size_t)orow * NDIM + c0 + ml]      = acc0[rg];
                    out[(size_t)orow * NDIM + c0 + 16 + ml] = acc1[rg];
                }
            }
        }
    }
}

extern "C" void kernel_launch(void* const* d_in, const int* in_sizes, int n_in,
                              void* d_out, int out_size, void* d_ws, size_t ws_size,
                              hipStream_t stream) {
    const float* x    = (const float*)d_in[0];
    const int*   tids = (const int*)d_in[1];
    const float* W    = (const float*)d_in[2];
    float*       out  = (float*)d_out;
    const int n_rows  = in_sizes[1];   // 2048

    int*            gcnt = (int*)d_ws;                            // 64 ints
    unsigned short* rows = (unsigned short*)((char*)d_ws + 256);  // 64 x 2048 ushort

    k_groups<<<dim3(1), dim3(256), 0, stream>>>(tids, n_rows, gcnt, rows);
    k_gemm<<<dim3(NDIM / 32, 64), dim3(256), 0, stream>>>(x, W, gcnt, rows, out);
}